// Round 8
// baseline (669.845 us; speedup 1.0000x reference)
//
#include <hip/hip_runtime.h>
#include <math.h>

// Problem constants
#define NB 4
#define NS 1024
#define ND 512
#define NE 8
#define NH 1536
#define NT 4096       // NB*NS
#define D6 3072

typedef _Float16 half_t;
typedef _Float16 f16x8 __attribute__((ext_vector_type(8)));
typedef _Float16 f16x4 __attribute__((ext_vector_type(4)));
typedef float    f32x4 __attribute__((ext_vector_type(4)));

#define LDH 40    // staging LDS row stride in halfs (80 B)
#define LDC 136   // epilogue C-tile stride in halfs (272 B, 16B-aligned)

// ---------------- K0: mods = silu(c) @ W_ada + b_ada  (B x 6D) ----------------
__global__ __launch_bounds__(256) void k_ada(const float* __restrict__ c,
    const float* __restrict__ Wada, const float* __restrict__ bada,
    float* __restrict__ mods)
{
  __shared__ float sc[ND];
  int tid = threadIdx.x;
  int idx = blockIdx.x * 256 + tid;
  int b = idx / D6;
  int j = idx - b * D6;
  for (int d = tid; d < ND; d += 256) {
    float v = c[b * ND + d];
    sc[d] = v / (1.f + expf(-v));
  }
  __syncthreads();
  float acc = bada[j];
  #pragma unroll 8
  for (int d = 0; d < ND; ++d)
    acc += sc[d] * Wada[(size_t)d * D6 + j];
  mods[b * D6 + j] = acc;
}

// ------ LN (+modulate). Outputs: fp32 (opt) and/or h/l fp16 planes (opt). ----
__global__ __launch_bounds__(256) void k_lnmod(const float* X, int xstride,
    float* Yf, half_t* Yh, half_t* Yl, int ystride,
    const float* __restrict__ w, const float* __restrict__ b,
    const float* __restrict__ mods, int sh_off, int sc_off)
{
  __shared__ float red[16];
  int tid = threadIdx.x;
  int row = blockIdx.x;
  int batch = row >> 10;
  const float* xr = X + (size_t)row * xstride;
  float x0 = xr[tid], x1 = xr[tid + 256];
  float s = x0 + x1, q = x0 * x0 + x1 * x1;
  #pragma unroll
  for (int off = 32; off > 0; off >>= 1) { s += __shfl_down(s, off, 64); q += __shfl_down(q, off, 64); }
  if ((tid & 63) == 0) { red[tid >> 6] = s; red[8 + (tid >> 6)] = q; }
  __syncthreads();
  if (tid == 0) {
    float S = red[0] + red[1] + red[2] + red[3];
    float Q = red[8] + red[9] + red[10] + red[11];
    float mean = S * (1.f / (float)ND);
    float var = Q * (1.f / (float)ND) - mean * mean;
    red[0] = mean; red[1] = rsqrtf(var + 1e-5f);
  }
  __syncthreads();
  float mean = red[0], rstd = red[1];
  int d0 = tid, d1 = tid + 256;
  float y0 = (x0 - mean) * rstd * w[d0] + b[d0];
  float y1 = (x1 - mean) * rstd * w[d1] + b[d1];
  if (mods) {
    const float* mb = mods + batch * D6;
    y0 = y0 * (1.f + mb[sc_off + d0]) + mb[sh_off + d0];
    y1 = y1 * (1.f + mb[sc_off + d1]) + mb[sh_off + d1];
  }
  size_t o0 = (size_t)row * ystride + d0, o1 = (size_t)row * ystride + d1;
  if (Yf) { Yf[o0] = y0; Yf[o1] = y1; }
  if (Yh) {
    half_t h0 = (half_t)y0, h1 = (half_t)y1;
    Yh[o0] = h0; Yh[o1] = h1;
    if (Yl) { Yl[o0] = (half_t)(y0 - (float)h0); Yl[o1] = (half_t)(y1 - (float)h1); }
  }
}

// ------ fused in-place LN of q and k halves of QKV (row stride 1536) ---------
__global__ __launch_bounds__(256) void k_lnqk(float* QKV,
    const float* __restrict__ qw, const float* __restrict__ qb,
    const float* __restrict__ kw, const float* __restrict__ kb)
{
  __shared__ float red[16];
  int tid = threadIdx.x;
  int row = blockIdx.x >> 1;
  int h = blockIdx.x & 1;
  const float* w = h ? kw : qw;
  const float* b = h ? kb : qb;
  float* xr = QKV + (size_t)row * 1536 + h * 512;
  float x0 = xr[tid], x1 = xr[tid + 256];
  float s = x0 + x1, q = x0 * x0 + x1 * x1;
  #pragma unroll
  for (int off = 32; off > 0; off >>= 1) { s += __shfl_down(s, off, 64); q += __shfl_down(q, off, 64); }
  if ((tid & 63) == 0) { red[tid >> 6] = s; red[8 + (tid >> 6)] = q; }
  __syncthreads();
  if (tid == 0) {
    float S = red[0] + red[1] + red[2] + red[3];
    float Q = red[8] + red[9] + red[10] + red[11];
    float mean = S * (1.f / (float)ND);
    float var = Q * (1.f / (float)ND) - mean * mean;
    red[0] = mean; red[1] = rsqrtf(var + 1e-5f);
  }
  __syncthreads();
  float mean = red[0], rstd = red[1];
  xr[tid]       = (x0 - mean) * rstd * w[tid] + b[tid];
  xr[tid + 256] = (x1 - mean) * rstd * w[tid + 256] + b[tid + 256];
}

// ---- transpose+split q,k: QKV[s][z*512..] -> (base + z*4MB)[c][s] h/l -------
__global__ __launch_bounds__(256) void k_tsplit2(const float* __restrict__ QKV,
    half_t* __restrict__ H0, half_t* __restrict__ L0)
{
  __shared__ float tile[32][33];
  int z = blockIdx.z;
  half_t* outH = H0 + (size_t)z * 4194304;
  half_t* outL = L0 + (size_t)z * 4194304;
  int col0 = z * 512;
  int s0 = blockIdx.x * 32, c0 = blockIdx.y * 32;
  int tid = threadIdx.x;
  int r = tid >> 5, c = tid & 31;
  #pragma unroll
  for (int p = 0; p < 4; ++p)
    tile[r + p * 8][c] = QKV[(size_t)(s0 + r + p * 8) * 1536 + col0 + c0 + c];
  __syncthreads();
  #pragma unroll
  for (int p = 0; p < 4; ++p) {
    float v = tile[c][r + p * 8];
    half_t h = (half_t)v;
    size_t o = (size_t)(c0 + r + p * 8) * NT + s0 + c;
    outH[o] = h; outL[o] = (half_t)(v - (float)h);
  }
}

// ---- 4x weight transpose+split into one 2048-row h/l buffer -----------------
__global__ __launch_bounds__(256) void k_wsplit4(const float* __restrict__ Wq,
    const float* __restrict__ Wk, const float* __restrict__ Wv,
    const float* __restrict__ Wo, half_t* __restrict__ outH, half_t* __restrict__ outL)
{
  __shared__ float tile[32][33];
  int z = blockIdx.z;
  const float* W = (z == 0) ? Wq : (z == 1) ? Wk : (z == 2) ? Wv : Wo;
  int rowoff = z * 512;
  int k0 = blockIdx.x * 32, n0 = blockIdx.y * 32;
  int tid = threadIdx.x;
  int r = tid >> 5, c = tid & 31;
  #pragma unroll
  for (int p = 0; p < 4; ++p)
    tile[r + p * 8][c] = W[(size_t)(k0 + r + p * 8) * ND + n0 + c];
  __syncthreads();
  #pragma unroll
  for (int p = 0; p < 4; ++p) {
    float v = tile[c][r + p * 8];
    half_t h = (half_t)v;
    size_t o = (size_t)(rowoff + n0 + r + p * 8) * ND + k0 + c;
    outH[o] = h; outL[o] = (half_t)(v - (float)h);
  }
}

// ---- v split: QKV[s][1024..1535] fp32 -> Vh/Vl [s][512] ---------------------
__global__ __launch_bounds__(256) void k_vsplit(const float* __restrict__ QKV,
    half_t* __restrict__ Vh, half_t* __restrict__ Vl)
{
  int i = blockIdx.x * 256 + threadIdx.x;
  int s = i >> 7, c = (i & 127) * 4;
  float4 v = *(const float4*)(QKV + (size_t)s * 1536 + 1024 + c);
  f16x4 h, l;
  h[0] = (half_t)v.x; l[0] = (half_t)(v.x - (float)h[0]);
  h[1] = (half_t)v.y; l[1] = (half_t)(v.y - (float)h[1]);
  h[2] = (half_t)v.z; l[2] = (half_t)(v.z - (float)h[2]);
  h[3] = (half_t)v.w; l[3] = (half_t)(v.w - (float)h[3]);
  *(f16x4*)(Vh + (size_t)s * ND + c) = h;
  *(f16x4*)(Vl + (size_t)s * ND + c) = l;
}

// ============ split-fp16 MFMA GEMM: C = A_hl(M,K) * B_hl(N,K)^T ==============
template<int MODE>
__global__ __launch_bounds__(256) void k_gemm_hl(
    const half_t* __restrict__ Ah, const half_t* __restrict__ Al, long long sAz,
    const half_t* __restrict__ Bh, const half_t* __restrict__ Bl, long long sBz,
    int lda, int ldb, int K,
    float* __restrict__ Cf, half_t* __restrict__ Ch, half_t* __restrict__ Cl,
    long long sCz, int ldc,
    const float* __restrict__ xres, const float* __restrict__ mods)
{
  int z = blockIdx.z;
  int m0 = blockIdx.x * 128, n0 = blockIdx.y * 128;
  __shared__ __align__(16) char smem[40960];
  half_t* Ash = (half_t*)smem;
  half_t* Asl = (half_t*)(smem + 10240);
  half_t* Bsh = (half_t*)(smem + 20480);
  half_t* Bsl = (half_t*)(smem + 30720);
  int tid = threadIdx.x;
  int lane = tid & 63, w = tid >> 6;
  int wm = (w >> 1) * 64, wn = (w & 1) * 64;
  int qd = lane >> 4, md = lane & 15;
  int rA0 = tid >> 2, sA0 = (tid & 3) * 8;
  int rA1 = rA0 + 64;

  const half_t* pAh0 = Ah + z * sAz + (size_t)(m0 + rA0) * lda + sA0;
  const half_t* pAh1 = Ah + z * sAz + (size_t)(m0 + rA1) * lda + sA0;
  const half_t* pAl0 = Al + z * sAz + (size_t)(m0 + rA0) * lda + sA0;
  const half_t* pAl1 = Al + z * sAz + (size_t)(m0 + rA1) * lda + sA0;
  const half_t* pBh0 = Bh + z * sBz + (size_t)(n0 + rA0) * ldb + sA0;
  const half_t* pBh1 = Bh + z * sBz + (size_t)(n0 + rA1) * ldb + sA0;
  const half_t* pBl0 = Bl + z * sBz + (size_t)(n0 + rA0) * ldb + sA0;
  const half_t* pBl1 = Bl + z * sBz + (size_t)(n0 + rA1) * ldb + sA0;

  f32x4 acc[4][4];
  #pragma unroll
  for (int i = 0; i < 4; ++i)
    #pragma unroll
    for (int j = 0; j < 4; ++j)
      #pragma unroll
      for (int p = 0; p < 4; ++p) acc[i][j][p] = 0.f;

  f16x8 rah0 = *(const f16x8*)pAh0, rah1 = *(const f16x8*)pAh1;
  f16x8 ral0 = *(const f16x8*)pAl0, ral1 = *(const f16x8*)pAl1;
  f16x8 rbh0 = *(const f16x8*)pBh0, rbh1 = *(const f16x8*)pBh1;
  f16x8 rbl0 = *(const f16x8*)pBl0, rbl1 = *(const f16x8*)pBl1;

  int iters = K >> 5;
  #pragma unroll 1
  for (int it = 0; it < iters; ++it) {
    __syncthreads();
    *(f16x8*)(Ash + rA0 * LDH + sA0) = rah0;
    *(f16x8*)(Ash + rA1 * LDH + sA0) = rah1;
    *(f16x8*)(Asl + rA0 * LDH + sA0) = ral0;
    *(f16x8*)(Asl + rA1 * LDH + sA0) = ral1;
    *(f16x8*)(Bsh + rA0 * LDH + sA0) = rbh0;
    *(f16x8*)(Bsh + rA1 * LDH + sA0) = rbh1;
    *(f16x8*)(Bsl + rA0 * LDH + sA0) = rbl0;
    *(f16x8*)(Bsl + rA1 * LDH + sA0) = rbl1;
    __syncthreads();
    if (it < iters - 1) {
      int k1 = (it + 1) * 32;
      rah0 = *(const f16x8*)(pAh0 + k1); rah1 = *(const f16x8*)(pAh1 + k1);
      ral0 = *(const f16x8*)(pAl0 + k1); ral1 = *(const f16x8*)(pAl1 + k1);
      rbh0 = *(const f16x8*)(pBh0 + k1); rbh1 = *(const f16x8*)(pBh1 + k1);
      rbl0 = *(const f16x8*)(pBl0 + k1); rbl1 = *(const f16x8*)(pBl1 + k1);
    }
    f16x8 ah[4], al[4], bh[4], bl[4];
    #pragma unroll
    for (int i = 0; i < 4; ++i) {
      ah[i] = *(const f16x8*)(Ash + (wm + 16 * i + md) * LDH + qd * 8);
      al[i] = *(const f16x8*)(Asl + (wm + 16 * i + md) * LDH + qd * 8);
    }
    #pragma unroll
    for (int j = 0; j < 4; ++j) {
      bh[j] = *(const f16x8*)(Bsh + (wn + 16 * j + md) * LDH + qd * 8);
      bl[j] = *(const f16x8*)(Bsl + (wn + 16 * j + md) * LDH + qd * 8);
    }
    #pragma unroll
    for (int i = 0; i < 4; ++i)
      #pragma unroll
      for (int j = 0; j < 4; ++j) {
        acc[i][j] = __builtin_amdgcn_mfma_f32_16x16x32_f16(ah[i], bh[j], acc[i][j], 0, 0, 0);
        acc[i][j] = __builtin_amdgcn_mfma_f32_16x16x32_f16(ah[i], bl[j], acc[i][j], 0, 0, 0);
        acc[i][j] = __builtin_amdgcn_mfma_f32_16x16x32_f16(al[i], bh[j], acc[i][j], 0, 0, 0);
      }
  }

  if (MODE == 1) {
    half_t* Cs = (half_t*)smem;
    __syncthreads();
    #pragma unroll
    for (int i = 0; i < 4; ++i)
      #pragma unroll
      for (int j = 0; j < 4; ++j)
        #pragma unroll
        for (int p = 0; p < 4; ++p)
          Cs[(wm + 16 * i + qd * 4 + p) * LDC + wn + 16 * j + md] = (half_t)acc[i][j][p];
    __syncthreads();
    #pragma unroll
    for (int it2 = 0; it2 < 8; ++it2) {
      int chunk = it2 * 256 + tid;
      int r = chunk >> 4, c8 = (chunk & 15) * 8;
      *(f16x8*)(Ch + z * sCz + (size_t)(m0 + r) * ldc + n0 + c8) = *(const f16x8*)(Cs + r * LDC + c8);
    }
    __syncthreads();
    #pragma unroll
    for (int i = 0; i < 4; ++i)
      #pragma unroll
      for (int j = 0; j < 4; ++j)
        #pragma unroll
        for (int p = 0; p < 4; ++p) {
          float v = acc[i][j][p];
          half_t h = (half_t)v;
          Cs[(wm + 16 * i + qd * 4 + p) * LDC + wn + 16 * j + md] = (half_t)(v - (float)h);
        }
    __syncthreads();
    #pragma unroll
    for (int it2 = 0; it2 < 8; ++it2) {
      int chunk = it2 * 256 + tid;
      int r = chunk >> 4, c8 = (chunk & 15) * 8;
      *(f16x8*)(Cl + z * sCz + (size_t)(m0 + r) * ldc + n0 + c8) = *(const f16x8*)(Cs + r * LDC + c8);
    }
  } else {
    #pragma unroll
    for (int i = 0; i < 4; ++i)
      #pragma unroll
      for (int p = 0; p < 4; ++p) {
        int r = m0 + wm + 16 * i + qd * 4 + p;
        float* cp = Cf + z * sCz + (size_t)r * ldc + n0 + wn + md;
        if (MODE == 2) {
          int batch = r >> 10;
          const float* mb = mods + batch * D6 + 2 * ND;
          const float* xp = xres + (size_t)r * ldc + n0 + wn + md;
          #pragma unroll
          for (int j = 0; j < 4; ++j) {
            int col = wn + md + 16 * j;
            cp[16 * j] = xp[16 * j] + mb[n0 + col] * acc[i][j][p];
          }
        } else {
          #pragma unroll
          for (int j = 0; j < 4; ++j) cp[16 * j] = acc[i][j][p];
        }
      }
  }
}

// ---- softmax over rows of 512, input = 4 split-K partials; P as h/l fp16 ----
__global__ __launch_bounds__(256) void k_softmax512_sum4(const float* __restrict__ SC4,
    half_t* __restrict__ Ph, half_t* __restrict__ Pl)
{
  __shared__ float red[16];
  int tid = threadIdx.x;
  int row = blockIdx.x;             // 2048 = b*512 + d
  int b = row >> 9, d = row & 511;
  const float* r0 = SC4 + ((size_t)(b * 4 + 0) << 18) + (size_t)d * ND;
  const float* r1 = SC4 + ((size_t)(b * 4 + 1) << 18) + (size_t)d * ND;
  const float* r2 = SC4 + ((size_t)(b * 4 + 2) << 18) + (size_t)d * ND;
  const float* r3 = SC4 + ((size_t)(b * 4 + 3) << 18) + (size_t)d * ND;
  float x0 = r0[tid] + r1[tid] + r2[tid] + r3[tid];
  float x1 = r0[tid + 256] + r1[tid + 256] + r2[tid + 256] + r3[tid + 256];
  float m = fmaxf(x0, x1);
  #pragma unroll
  for (int off = 32; off > 0; off >>= 1) m = fmaxf(m, __shfl_down(m, off, 64));
  if ((tid & 63) == 0) red[tid >> 6] = m;
  __syncthreads();
  if (tid == 0) red[0] = fmaxf(fmaxf(red[0], red[1]), fmaxf(red[2], red[3]));
  __syncthreads();
  m = red[0];
  float e0 = expf(x0 - m), e1 = expf(x1 - m);
  float s = e0 + e1;
  #pragma unroll
  for (int off = 32; off > 0; off >>= 1) s += __shfl_down(s, off, 64);
  if ((tid & 63) == 0) red[8 + (tid >> 6)] = s;
  __syncthreads();
  if (tid == 0) red[8] = red[8] + red[9] + red[10] + red[11];
  __syncthreads();
  float inv = 1.f / red[8];
  float p0 = e0 * inv, p1 = e1 * inv;
  size_t base = (size_t)row * ND;
  half_t h0 = (half_t)p0, h1 = (half_t)p1;
  Ph[base + tid] = h0;       Pl[base + tid] = (half_t)(p0 - (float)h0);
  Ph[base + tid + 256] = h1; Pl[base + tid + 256] = (half_t)(p1 - (float)h1);
}

// -------- router logits = xm @ Wr + br  (T x 8) ------------------------------
__global__ __launch_bounds__(256) void k_router(const float* __restrict__ xm,
    const float* __restrict__ Wr, const float* __restrict__ br, float* __restrict__ logits)
{
  int idx = blockIdx.x * 256 + threadIdx.x;
  int t = idx >> 3, e = idx & 7;
  float acc = br[e];
  const float* xr = xm + (size_t)t * ND;
  #pragma unroll 4
  for (int d = 0; d < ND; ++d) acc += xr[d] * Wr[d * NE + e];
  logits[idx] = acc;
}

// -------- nrm[b,e] = sqrt(sum_s logits^2) ------------------------------------
__global__ __launch_bounds__(256) void k_colnorm(const float* __restrict__ logits,
    float* __restrict__ nrm)
{
  __shared__ float red[8];
  int tid = threadIdx.x;
  int b = blockIdx.x >> 3, e = blockIdx.x & 7;
  float acc = 0.f;
  for (int s = tid; s < NS; s += 256) {
    float l = logits[((size_t)(b << 10) + s) * NE + e];
    acc += l * l;
  }
  #pragma unroll
  for (int off = 32; off > 0; off >>= 1) acc += __shfl_down(acc, off, 64);
  if ((tid & 63) == 0) red[tid >> 6] = acc;
  __syncthreads();
  if (tid == 0) nrm[b * NE + e] = sqrtf(red[0] + red[1] + red[2] + red[3]);
}

__global__ void k_zero16(int* p) { if (threadIdx.x < 16) p[threadIdx.x] = 0; }

// -------- per-token: probs, top-2, expert counts -----------------------------
__global__ __launch_bounds__(256) void k_top2(const float* __restrict__ logits,
    const float* __restrict__ nrm, float* __restrict__ probs,
    float* __restrict__ wsel, int* __restrict__ isel, int* __restrict__ cnt)
{
  int t = blockIdx.x * 256 + threadIdx.x;
  int b = t >> 10;
  float p[NE];
  float mx = -1e30f;
  #pragma unroll
  for (int e = 0; e < NE; ++e) {
    float l = logits[t * NE + e] / fmaxf(nrm[b * NE + e], 1e-12f);
    p[e] = l;
    mx = fmaxf(mx, l);
  }
  float s = 0.f;
  #pragma unroll
  for (int e = 0; e < NE; ++e) { p[e] = expf(p[e] - mx); s += p[e]; }
  float inv = 1.f / s;
  #pragma unroll
  for (int e = 0; e < NE; ++e) { p[e] *= inv; probs[t * NE + e] = p[e]; }
  int i1 = 0;
  #pragma unroll
  for (int e = 1; e < NE; ++e) if (p[e] > p[i1]) i1 = e;
  int i2 = (i1 == 0) ? 1 : 0;
  #pragma unroll
  for (int e = 0; e < NE; ++e) if (e != i1 && p[e] > p[i2]) i2 = e;
  wsel[t * 2] = p[i1]; wsel[t * 2 + 1] = p[i2];
  isel[t * 2] = i1;    isel[t * 2 + 1] = i2;
  atomicAdd(&cnt[i1], 1); atomicAdd(&cnt[i2], 1);
}

__global__ void k_scan(const int* __restrict__ cnt, int* __restrict__ offs)
{
  if (threadIdx.x == 0) {
    int a = 0;
    for (int e = 0; e < NE; ++e) { offs[e] = a; a += cnt[e]; }
    offs[NE] = a;
  }
}

// fill: compacted per-expert token lists + token->slot inverse map
__global__ __launch_bounds__(256) void k_fill(const int* __restrict__ isel,
    const int* __restrict__ offs, int* __restrict__ cnt2,
    int* __restrict__ list, int* __restrict__ inv)
{
  int idx = blockIdx.x * 256 + threadIdx.x;   // 8192 = token*2 + k
  int e = isel[idx];
  int pos = atomicAdd(&cnt2[e], 1);
  int slot = offs[e] + pos;
  list[slot] = idx >> 1;
  inv[idx] = slot;
}

// -------- aux = sum_{s,e} (1/E - mean_b probs)^2 -----------------------------
__global__ __launch_bounds__(256) void k_aux(const float* __restrict__ probs,
    float* __restrict__ outAux)
{
  __shared__ float red[8];
  int tid = threadIdx.x;
  float acc = 0.f;
  for (int s = tid; s < NS; s += 256) {
    #pragma unroll
    for (int e = 0; e < NE; ++e) {
      float a = probs[(size_t)s * NE + e] + probs[(size_t)(NS + s) * NE + e]
              + probs[(size_t)(2 * NS + s) * NE + e] + probs[(size_t)(3 * NS + s) * NE + e];
      float d = 0.125f - a * 0.25f;
      acc += d * d;
    }
  }
  #pragma unroll
  for (int off = 32; off > 0; off >>= 1) acc += __shfl_down(acc, off, 64);
  if ((tid & 63) == 0) red[tid >> 6] = acc;
  __syncthreads();
  if (tid == 0) *outAux = red[0] + red[1] + red[2] + red[3];
}

// ---- transpose+cast W1 and W3 in one launch: z = sel*8 + e ------------------
__global__ __launch_bounds__(256) void k_tcast13(const float* __restrict__ W1,
    const float* __restrict__ W3, half_t* __restrict__ W1t, half_t* __restrict__ W3t)
{
  __shared__ float tile[32][33];
  int z = blockIdx.z;
  int sel = z >> 3, e = z & 7;
  const float* We = (sel ? W3 : W1) + (size_t)e * ND * NH;
  half_t* Wte = (sel ? W3t : W1t) + (size_t)e * ND * NH;
  int k0 = blockIdx.x * 32, n0 = blockIdx.y * 32;
  int tid = threadIdx.x;
  int r = tid >> 5, c = tid & 31;
  #pragma unroll
  for (int p = 0; p < 4; ++p)
    tile[r + p * 8][c] = We[(size_t)(k0 + r + p * 8) * NH + n0 + c];
  __syncthreads();
  #pragma unroll
  for (int p = 0; p < 4; ++p)
    Wte[(size_t)(n0 + r + p * 8) * ND + k0 + c] = (half_t)tile[c][r + p * 8];
}

// ---- transpose+cast W2[e][NH][ND] -> W2t[e][ND][NH] -------------------------
__global__ __launch_bounds__(256) void k_tcastW2(const float* __restrict__ W,
    half_t* __restrict__ Wt)
{
  __shared__ float tile[32][33];
  const float* We = W + (size_t)blockIdx.z * NH * ND;
  half_t* Wte = Wt + (size_t)blockIdx.z * NH * ND;
  int k0 = blockIdx.x * 32, n0 = blockIdx.y * 32;
  int tid = threadIdx.x;
  int r = tid >> 5, c = tid & 31;
  #pragma unroll
  for (int p = 0; p < 4; ++p)
    tile[r + p * 8][c] = We[(size_t)(k0 + r + p * 8) * ND + n0 + c];
  __syncthreads();
  #pragma unroll
  for (int p = 0; p < 4; ++p)
    Wte[(size_t)(n0 + r + p * 8) * NH + k0 + c] = (half_t)tile[c][r + p * 8];
}

// ===== fused FFN, DIRECT MFMA-layout global loads (no LDS in K-loop) =========
// gate = f16( sin(xm@W1^T) * (xm@W3^T) ). flat grid, expert = bx & 7.
__global__ __launch_bounds__(256) void k_ffn_direct(const half_t* __restrict__ xmh,
    const half_t* __restrict__ W1t, const half_t* __restrict__ W3t,
    const int* __restrict__ list, const int* __restrict__ offs,
    half_t* __restrict__ gate)
{
  int bx = blockIdx.x;            // 1536 = 8 e * 16 m * 12 n
  int e = bx & 7;
  int r6 = bx >> 3;
  int m0 = (r6 & 15) * 128;
  int n0 = (r6 >> 4) * 128;
  int base = offs[e], ne = offs[e + 1] - base;
  if (m0 >= ne) return;
  __shared__ __align__(16) half_t Cs[128 * LDC];   // epilogue only
  int tid = threadIdx.x;
  int lane = tid & 63, w = tid >> 6;
  int wm = (w >> 1) * 64, wn = (w & 1) * 64;
  int qd = lane >> 4, md = lane & 15;

  // per-lane fragment base pointers (A rows via token gather; B rows direct)
  const half_t* pA[4];
  #pragma unroll
  for (int i = 0; i < 4; ++i) {
    int r = m0 + wm + 16 * i + md;
    int t = (r < ne) ? list[base + r] : 0;
    pA[i] = xmh + (size_t)t * ND + qd * 8;
  }
  const half_t* pB1[4];
  const half_t* pB3[4];
  #pragma unroll
  for (int j = 0; j < 4; ++j) {
    size_t nrow = (size_t)e * NH + n0 + wn + 16 * j + md;
    pB1[j] = W1t + nrow * ND + qd * 8;
    pB3[j] = W3t + nrow * ND + qd * 8;
  }

  f32x4 acc1[4][4], acc3[4][4];
  #pragma unroll
  for (int i = 0; i < 4; ++i)
    #pragma unroll
    for (int j = 0; j < 4; ++j)
      #pragma unroll
      for (int p = 0; p < 4; ++p) { acc1[i][j][p] = 0.f; acc3[i][j][p] = 0.f; }

  #pragma unroll 4
  for (int k0 = 0; k0 < ND; k0 += 32) {
    f16x8 a[4], b1[4], b3[4];
    #pragma unroll
    for (int i = 0; i < 4; ++i) a[i] = *(const f16x8*)(pA[i] + k0);
    #pragma unroll
    for (int j = 0; j < 4; ++j) {
      b1[j] = *(const f16x8*)(pB1[j] + k0);
      b3[j] = *(const f16x8*)(pB3[j] + k0);
    }
    #pragma unroll
    for (int i = 0; i < 4; ++i)
      #pragma unroll
      for (int j = 0; j < 4; ++j) {
        acc1[i][j] = __builtin_amdgcn_mfma_f32_16x16x32_f16(a[i], b1[j], acc1[i][j], 0, 0, 0);
        acc3[i][j] = __builtin_amdgcn_mfma_f32_16x16x32_f16(a[i], b3[j], acc3[i][j], 0, 0, 0);
      }
  }
  // epilogue: sin-gate, stage to LDS, vectorized coalesced store
  #pragma unroll
  for (int i = 0; i < 4; ++i)
    #pragma unroll
    for (int j = 0; j < 4; ++j)
      #pragma unroll
      for (int p = 0; p < 4; ++p) {
        int rr = wm + 16 * i + qd * 4 + p;
        int cc = wn + 16 * j + md;
        Cs[rr * LDC + cc] = (half_t)(__sinf(acc1[i][j][p]) * acc3[i][j][p]);
      }
  __syncthreads();
  #pragma unroll
  for (int it = 0; it < 8; ++it) {
    int chunk = it * 256 + tid;
    int rr = chunk >> 4, c8 = (chunk & 15) * 8;
    if (m0 + rr < ne)
      *(f16x8*)(gate + (size_t)(base + m0 + rr) * NH + n0 + c8) = *(const f16x8*)(Cs + rr * LDC + c8);
  }
}

// ===== MoE stage 2, DIRECT loads (no LDS at all): P = gate @ W2_e^T ==========
__global__ __launch_bounds__(256) void k_moe2_direct(const half_t* __restrict__ gate,
    const half_t* __restrict__ W2t, const int* __restrict__ offs,
    float* __restrict__ P)
{
  int bx = blockIdx.x;            // 512 = 8 e * 16 m * 4 n
  int e = bx & 7;
  int r6 = bx >> 3;
  int m0 = (r6 & 15) * 128;
  int n0 = (r6 >> 4) * 128;
  int base = offs[e], ne = offs[e + 1] - base;
  if (m0 >= ne) return;
  int tid = threadIdx.x;
  int lane = tid & 63, w = tid >> 6;
  int wm = (w >> 1) * 64, wn = (w & 1) * 64;
  int qd = lane >> 4, md = lane & 15;

  const half_t* pA[4];
  #pragma unroll
  for (int i = 0; i < 4; ++i) {
    int r = m0 + wm + 16 * i + md;
    int rr = (r < ne) ? r : 0;
    pA[i] = gate + (size_t)(base + rr) * NH + qd * 8;
  }
  const half_t* pB[4];
  #pragma unroll
  for (int j = 0; j < 4; ++j) {
    size_t nrow = (size_t)e * ND + n0 + wn + 16 * j + md;
    pB[j] = W2t + nrow * NH + qd * 8;
  }

  f32x4 acc[4][4];
  #pragma unroll
  for (int i = 0; i < 4; ++i)
    #pragma unroll
    for (int j = 0; j < 4; ++j)
      #pragma unroll
      for (int p = 0; p < 4; ++p) acc[i][j][p] = 0.f;

  #pragma unroll 4
  for (int k0 = 0; k0 < NH; k0 += 32) {
    f16x8 a[4], b[4];
    #pragma unroll
    for (int i = 0; i < 4; ++i) a[i] = *(const f16x8*)(pA[i] + k0);
    #pragma unroll
    for (int j = 0; j < 4; ++j) b[j] = *(const f16x8*)(pB[j] + k0);
    #pragma unroll
    for (int i = 0; i < 4; ++i)
      #pragma unroll
      for (int j = 0; j < 4; ++j)
        acc[i][j] = __builtin_amdgcn_mfma_f32_16x16x32_f16(a[i], b[j], acc[i][j], 0, 0, 0);
  }
  // plain coalesced fp32 stores (each wave store = 4 full 64B lines)
  #pragma unroll
  for (int i = 0; i < 4; ++i)
    #pragma unroll
    for (int p = 0; p < 4; ++p) {
      int gr = m0 + wm + 16 * i + qd * 4 + p;
      if (gr < ne) {
        float* pp = P + (size_t)(base + gr) * ND + n0 + wn + md;
        #pragma unroll
        for (int j = 0; j < 4; ++j)
          pp[16 * j] = acc[i][j][p];
      }
    }
}

// ---- reduce: out[t][:] = w1 * P[slot1][:] + w2 * P[slot2][:] ----------------
__global__ __launch_bounds__(256) void k_moe_reduce(const float* __restrict__ P,
    const int* __restrict__ inv, const float* __restrict__ wsel,
    float* __restrict__ out)
{
  int i = blockIdx.x * 256 + threadIdx.x;   // 4096 * 128 float4s
  int t = i >> 7, d4 = i & 127;
  int s1 = inv[t * 2], s2 = inv[t * 2 + 1];
  float w1 = wsel[t * 2], w2 = wsel[t * 2 + 1];
  const float4* P4 = (const float4*)P;
  float4 a = P4[(size_t)s1 * 128 + d4];
  float4 b = P4[(size_t)s2 * 128 + d4];
  float4 o;
  o.x = w1 * a.x + w2 * b.x;
  o.y = w1 * a.y + w2 * b.y;
  o.z = w1 * a.z + w2 * b.z;
  o.w = w1 * a.w + w2 * b.w;
  ((float4*)out)[i] = o;
}

// ---------------- workspace layout (byte offsets, peak ~63.4 MB) -------------
static const size_t BO_MODS  = 0;          // 49152 B fp32 mods
static const size_t BO_HH    = 65536;      // Hh 4 MB   } region B (8 MB)
static const size_t BO_HL2   = 4259840;    // Hl 4 MB   }
static const size_t BO_PH    = 4259840;    // Ph 2 MB (after Hl dead)
static const size_t BO_PL    = 6357056;    // Pl 2 MB
static const size_t BO_WALLH = 8454144;    // 2 MB: q|k|v|o transposed h (2048 rows)
static const size_t BO_WALLL = 10551296;   // 2 MB: l planes
static const size_t BO_QKV   = 12648448;   // fp32 [4096][1536] 25.17 MB (region D)
static const size_t BO_A0H   = 12648448;   // attn0 h 4 MB (after QKV dead)
static const size_t BO_A0L   = 16842752;   // attn0 l 4 MB
static const size_t BO_SC4   = 21037056;   // 16 MB fp32: 16 x [512][512] split-K partials
static const size_t BO_X2    = 21037056;   // fp32 8 MB (after SC4 dead)
static const size_t BO_XM    = 29425664;   // fp32 8 MB (after SC4 dead)
static const size_t BO_QTH   = 37814272;   // qT h 4 MB } region E (16 MB)
static const size_t BO_QTL   = 42008576;
static const size_t BO_KTH   = 46202880;
static const size_t BO_KTL   = 50397184;
static const size_t BO_VH    = 54591488;   // region F (8 MB)
static const size_t BO_VL    = 58785792;
// MoE phase (aliases):
static const size_t BO_W1T   = 37814272;   // 12.58 MB (qT/kT dead after scores)
static const size_t BO_XMH   = 50397184;   // 4 MB (kT_l dead)
static const size_t BO_W3T   = 65536;      // 12.58 MB = region B+C (dead after apply/Wo)
static const size_t BO_GATE  = 12648448;   // 25.17 MB = region D
static const size_t BO_W2T   = 65536;      // 12.58 MB (overwrites W3T after ffn)
static const size_t BO_P     = 37814272;   // 16.78 MB fp32 (W1T+XMH dead after ffn)
// small buffers:
static const size_t BO_LOGI  = 62980096;
static const size_t BO_NRM   = 63111168;
static const size_t BO_PROB  = 63111296;
static const size_t BO_WSEL  = 63242368;
static const size_t BO_INTS  = 63307904;   // ints: isel 8192|cnt 8|cnt2 8|offs 16|list 8192|inv 8192

extern "C" void kernel_launch(void* const* d_in, const int* in_sizes, int n_in,
                              void* d_out, int out_size, void* d_ws, size_t ws_size,
                              hipStream_t stream)
{
  const float* x    = (const float*)d_in[0];
  const float* c    = (const float*)d_in[1];
  const float* Wada = (const float*)d_in[2];
  const float* bada = (const float*)d_in[3];
  const float* Wq   = (const float*)d_in[4];
  const float* Wk   = (const float*)d_in[5];
  const float* Wv   = (const float*)d_in[6];
  const float* Wo   = (const float*)d_in[7];
  const float* qn_w = (const float*)d_in[8];
  const float* qn_b = (const float*)d_in[9];
  const float* kn_w = (const float*)d_in[10];
  const float* kn_b = (const float*)d_in[11];
  const float* an_w = (const float*)d_in[12];
  const float* an_b = (const float*)d_in[13];
  const float* fn_w = (const float*)d_in[14];
  const float* fn_b = (const float*)d_in[15];
  const float* Wr   = (const float*)d_in[16];
  const float* br   = (const float*)d_in[17];
  const float* W1   = (const float*)d_in[18];
  const float* W2   = (const float*)d_in[19];
  const float* W3   = (const float*)d_in[20];
  float* out = (float*)d_out;
  char*  ws8 = (char*)d_ws;
  float* MODS = (float*)(ws8 + BO_MODS);
  half_t* Hh = (half_t*)(ws8 + BO_HH),   *Hl = (half_t*)(ws8 + BO_HL2);
  half_t* Ph = (half_t*)(ws8 + BO_PH),   *Pl = (half_t*)(ws8 + BO_PL);
  half_t* WALLH = (half_t*)(ws8 + BO_WALLH), *WALLL = (half_t*)(ws8 + BO_WALLL);
  half_t* WoTh = WALLH + (size_t)1536 * ND,  *WoTl = WALLL + (size_t)1536 * ND;
  float* QKV = (float*)(ws8 + BO_QKV);
  half_t* A0h = (half_t*)(ws8 + BO_A0H), *A0l = (half_t*)(ws8 + BO_A0L);
  float* SC4 = (float*)(ws8 + BO_SC4);
  float* X2  = (float*)(ws8 + BO_X2);
  float* XM  = (float*)(ws8 + BO_XM);
  half_t* qTh = (half_t*)(ws8 + BO_QTH), *qTl = (half_t*)(ws8 + BO_QTL);
  half_t* kTh = (half_t*)(ws8 + BO_KTH), *kTl = (half_t*)(ws8 + BO_KTL);
  half_t* Vh  = (half_t*)(ws8 + BO_VH),  *Vl  = (half_t*)(ws8 + BO_VL);
  half_t* W1T = (half_t*)(ws8 + BO_W1T);
  half_t* W3T = (half_t*)(ws8 + BO_W3T);
  half_t* W2T = (half_t*)(ws8 + BO_W2T);
  half_t* XMH = (half_t*)(ws8 + BO_XMH);
  half_t* GATEH = (half_t*)(ws8 + BO_GATE);
  float* PBUF = (float*)(ws8 + BO_P);
  float* LOGI = (float*)(ws8 + BO_LOGI);
  float* NRM  = (float*)(ws8 + BO_NRM);
  float* PROB = (float*)(ws8 + BO_PROB);
  float* WSEL = (float*)(ws8 + BO_WSEL);
  int* ib   = (int*)(ws8 + BO_INTS);
  int* isel = ib;
  int* cnt  = ib + 8192;
  int* cnt2 = ib + 8200;
  int* offs = ib + 8208;
  int* list = ib + 8224;
  int* inv  = ib + 16416;

  k_ada<<<48, 256, 0, stream>>>(c, Wada, bada, MODS);
  k_wsplit4<<<dim3(16, 16, 4), 256, 0, stream>>>(Wq, Wk, Wv, Wo, WALLH, WALLL);
  // h = modulate(LN(x)) -> h/l planes
  k_lnmod<<<NT, 256, 0, stream>>>(x, ND, nullptr, Hh, Hl, ND, an_w, an_b, MODS, 0, 512);
  // fused QKV: [4096][1536]
  k_gemm_hl<0><<<dim3(32, 12, 1), 256, 0, stream>>>(Hh, Hl, 0, WALLH, WALLL, 0,
      ND, ND, ND, QKV, nullptr, nullptr, 0, 1536, nullptr, nullptr);
  // fused row-LN of q and k halves (in place)
  k_lnqk<<<2 * NT, 256, 0, stream>>>(QKV, qn_w, qn_b, kn_w, kn_b);
  // transpose+split q,k to [d][s]; split v
  k_tsplit2<<<dim3(128, 16, 2), 256, 0, stream>>>(QKV, qTh, qTl);
  k_vsplit<<<2048, 256, 0, stream>>>(QKV, Vh, Vl);
  // scores: split-K x4 (z = b*4+kh; A/B offset z*256 = b*1024+kh*256)
  k_gemm_hl<0><<<dim3(4, 4, 16), 256, 0, stream>>>(qTh, qTl, 256, kTh, kTl, 256,
      NT, NT, 256, SC4, nullptr, nullptr, 262144, ND, nullptr, nullptr);
  k_softmax512_sum4<<<2048, 256, 0, stream>>>(SC4, Ph, Pl);
  // apply: attn0[s][d] = sum_e v[s,e] P[d,e]
  k_gemm_hl<1><<<dim3(8, 4, 4), 256, 0, stream>>>(Vh, Vl, 524288, Ph, Pl, 262144,
      ND, ND, ND, nullptr, A0h, A0l, 524288, ND, nullptr, nullptr);
  // Wo + residual: X2 = x + g_msa * (attn0 @ Wo)
  k_gemm_hl<2><<<dim3(32, 4, 1), 256, 0, stream>>>(A0h, A0l, 0, WoTh, WoTl, 0,
      ND, ND, ND, X2, nullptr, nullptr, 0, ND, x, MODS);
  // xm = modulate(LN(X2)) -> fp32 (router) + fp16 (ffn)
  k_lnmod<<<NT, 256, 0, stream>>>(X2, ND, XM, XMH, nullptr, ND, fn_w, fn_b, MODS, 1536, 2048);
  // routing
  k_router<<<128, 256, 0, stream>>>(XM, Wr, br, LOGI);
  k_zero16<<<1, 64, 0, stream>>>(cnt);
  k_colnorm<<<32, 256, 0, stream>>>(LOGI, NRM);
  k_top2<<<16, 256, 0, stream>>>(LOGI, NRM, PROB, WSEL, isel, cnt);
  k_scan<<<1, 64, 0, stream>>>(cnt, offs);
  k_fill<<<32, 256, 0, stream>>>(isel, offs, cnt2, list, inv);
  k_aux<<<1, 256, 0, stream>>>(PROB, out + (size_t)NT * ND);
  // MoE: direct-load fused gate, atomic-free down-proj, weighted combine
  k_tcast13<<<dim3(16, 48, 16), 256, 0, stream>>>(W1, W3, W1T, W3T);
  k_ffn_direct<<<1536, 256, 0, stream>>>(XMH, W1T, W3T, list, offs, GATEH);
  k_tcastW2<<<dim3(48, 16, 8), 256, 0, stream>>>(W2, W2T);  // W3T dead now
  k_moe2_direct<<<512, 256, 0, stream>>>(GATEH, W2T, offs, PBUF);
  k_moe_reduce<<<2048, 256, 0, stream>>>(PBUF, inv, WSEL, out);
}

// Round 9
// 563.518 us; speedup vs baseline: 1.1887x; 1.1887x over previous
//
#include <hip/hip_runtime.h>
#include <math.h>

// Problem constants
#define NB 4
#define NS 1024
#define ND 512
#define NE 8
#define NH 1536
#define NT 4096       // NB*NS
#define D6 3072

typedef _Float16 half_t;
typedef _Float16 f16x8 __attribute__((ext_vector_type(8)));
typedef _Float16 f16x4 __attribute__((ext_vector_type(4)));
typedef float    f32x4 __attribute__((ext_vector_type(4)));

#define LDH 40    // staging LDS row stride in halfs (80 B)
#define LDC 136   // epilogue C-tile stride in halfs (272 B, 16B-aligned)

// ---------------- K0: mods = silu(c) @ W_ada + b_ada  (B x 6D) ----------------
__global__ __launch_bounds__(256) void k_ada(const float* __restrict__ c,
    const float* __restrict__ Wada, const float* __restrict__ bada,
    float* __restrict__ mods)
{
  __shared__ float sc[ND];
  int tid = threadIdx.x;
  int idx = blockIdx.x * 256 + tid;
  int b = idx / D6;
  int j = idx - b * D6;
  for (int d = tid; d < ND; d += 256) {
    float v = c[b * ND + d];
    sc[d] = v / (1.f + expf(-v));
  }
  __syncthreads();
  float acc = bada[j];
  #pragma unroll 8
  for (int d = 0; d < ND; ++d)
    acc += sc[d] * Wada[(size_t)d * D6 + j];
  mods[b * D6 + j] = acc;
}

// ------ LN (+modulate). Outputs: fp32 (opt) and/or h/l fp16 planes (opt). ----
__global__ __launch_bounds__(256) void k_lnmod(const float* X, int xstride,
    float* Yf, half_t* Yh, half_t* Yl, int ystride,
    const float* __restrict__ w, const float* __restrict__ b,
    const float* __restrict__ mods, int sh_off, int sc_off)
{
  __shared__ float red[16];
  int tid = threadIdx.x;
  int row = blockIdx.x;
  int batch = row >> 10;
  const float* xr = X + (size_t)row * xstride;
  float x0 = xr[tid], x1 = xr[tid + 256];
  float s = x0 + x1, q = x0 * x0 + x1 * x1;
  #pragma unroll
  for (int off = 32; off > 0; off >>= 1) { s += __shfl_down(s, off, 64); q += __shfl_down(q, off, 64); }
  if ((tid & 63) == 0) { red[tid >> 6] = s; red[8 + (tid >> 6)] = q; }
  __syncthreads();
  if (tid == 0) {
    float S = red[0] + red[1] + red[2] + red[3];
    float Q = red[8] + red[9] + red[10] + red[11];
    float mean = S * (1.f / (float)ND);
    float var = Q * (1.f / (float)ND) - mean * mean;
    red[0] = mean; red[1] = rsqrtf(var + 1e-5f);
  }
  __syncthreads();
  float mean = red[0], rstd = red[1];
  int d0 = tid, d1 = tid + 256;
  float y0 = (x0 - mean) * rstd * w[d0] + b[d0];
  float y1 = (x1 - mean) * rstd * w[d1] + b[d1];
  if (mods) {
    const float* mb = mods + batch * D6;
    y0 = y0 * (1.f + mb[sc_off + d0]) + mb[sh_off + d0];
    y1 = y1 * (1.f + mb[sc_off + d1]) + mb[sh_off + d1];
  }
  size_t o0 = (size_t)row * ystride + d0, o1 = (size_t)row * ystride + d1;
  if (Yf) { Yf[o0] = y0; Yf[o1] = y1; }
  if (Yh) {
    half_t h0 = (half_t)y0, h1 = (half_t)y1;
    Yh[o0] = h0; Yh[o1] = h1;
    if (Yl) { Yl[o0] = (half_t)(y0 - (float)h0); Yl[o1] = (half_t)(y1 - (float)h1); }
  }
}

// ------ fused in-place LN of q and k halves of QKV (row stride 1536) ---------
__global__ __launch_bounds__(256) void k_lnqk(float* QKV,
    const float* __restrict__ qw, const float* __restrict__ qb,
    const float* __restrict__ kw, const float* __restrict__ kb)
{
  __shared__ float red[16];
  int tid = threadIdx.x;
  int row = blockIdx.x >> 1;
  int h = blockIdx.x & 1;
  const float* w = h ? kw : qw;
  const float* b = h ? kb : qb;
  float* xr = QKV + (size_t)row * 1536 + h * 512;
  float x0 = xr[tid], x1 = xr[tid + 256];
  float s = x0 + x1, q = x0 * x0 + x1 * x1;
  #pragma unroll
  for (int off = 32; off > 0; off >>= 1) { s += __shfl_down(s, off, 64); q += __shfl_down(q, off, 64); }
  if ((tid & 63) == 0) { red[tid >> 6] = s; red[8 + (tid >> 6)] = q; }
  __syncthreads();
  if (tid == 0) {
    float S = red[0] + red[1] + red[2] + red[3];
    float Q = red[8] + red[9] + red[10] + red[11];
    float mean = S * (1.f / (float)ND);
    float var = Q * (1.f / (float)ND) - mean * mean;
    red[0] = mean; red[1] = rsqrtf(var + 1e-5f);
  }
  __syncthreads();
  float mean = red[0], rstd = red[1];
  xr[tid]       = (x0 - mean) * rstd * w[tid] + b[tid];
  xr[tid + 256] = (x1 - mean) * rstd * w[tid + 256] + b[tid + 256];
}

// ---- transpose+split q,k: QKV[s][z*512..] -> (base + z*4MB)[c][s] h/l -------
__global__ __launch_bounds__(256) void k_tsplit2(const float* __restrict__ QKV,
    half_t* __restrict__ H0, half_t* __restrict__ L0)
{
  __shared__ float tile[32][33];
  int z = blockIdx.z;
  half_t* outH = H0 + (size_t)z * 4194304;
  half_t* outL = L0 + (size_t)z * 4194304;
  int col0 = z * 512;
  int s0 = blockIdx.x * 32, c0 = blockIdx.y * 32;
  int tid = threadIdx.x;
  int r = tid >> 5, c = tid & 31;
  #pragma unroll
  for (int p = 0; p < 4; ++p)
    tile[r + p * 8][c] = QKV[(size_t)(s0 + r + p * 8) * 1536 + col0 + c0 + c];
  __syncthreads();
  #pragma unroll
  for (int p = 0; p < 4; ++p) {
    float v = tile[c][r + p * 8];
    half_t h = (half_t)v;
    size_t o = (size_t)(c0 + r + p * 8) * NT + s0 + c;
    outH[o] = h; outL[o] = (half_t)(v - (float)h);
  }
}

// ---- 4x weight transpose+split into one 2048-row h/l buffer -----------------
__global__ __launch_bounds__(256) void k_wsplit4(const float* __restrict__ Wq,
    const float* __restrict__ Wk, const float* __restrict__ Wv,
    const float* __restrict__ Wo, half_t* __restrict__ outH, half_t* __restrict__ outL)
{
  __shared__ float tile[32][33];
  int z = blockIdx.z;
  const float* W = (z == 0) ? Wq : (z == 1) ? Wk : (z == 2) ? Wv : Wo;
  int rowoff = z * 512;
  int k0 = blockIdx.x * 32, n0 = blockIdx.y * 32;
  int tid = threadIdx.x;
  int r = tid >> 5, c = tid & 31;
  #pragma unroll
  for (int p = 0; p < 4; ++p)
    tile[r + p * 8][c] = W[(size_t)(k0 + r + p * 8) * ND + n0 + c];
  __syncthreads();
  #pragma unroll
  for (int p = 0; p < 4; ++p) {
    float v = tile[c][r + p * 8];
    half_t h = (half_t)v;
    size_t o = (size_t)(rowoff + n0 + r + p * 8) * ND + k0 + c;
    outH[o] = h; outL[o] = (half_t)(v - (float)h);
  }
}

// ---- v split: QKV[s][1024..1535] fp32 -> Vh/Vl [s][512] ---------------------
__global__ __launch_bounds__(256) void k_vsplit(const float* __restrict__ QKV,
    half_t* __restrict__ Vh, half_t* __restrict__ Vl)
{
  int i = blockIdx.x * 256 + threadIdx.x;
  int s = i >> 7, c = (i & 127) * 4;
  float4 v = *(const float4*)(QKV + (size_t)s * 1536 + 1024 + c);
  f16x4 h, l;
  h[0] = (half_t)v.x; l[0] = (half_t)(v.x - (float)h[0]);
  h[1] = (half_t)v.y; l[1] = (half_t)(v.y - (float)h[1]);
  h[2] = (half_t)v.z; l[2] = (half_t)(v.z - (float)h[2]);
  h[3] = (half_t)v.w; l[3] = (half_t)(v.w - (float)h[3]);
  *(f16x4*)(Vh + (size_t)s * ND + c) = h;
  *(f16x4*)(Vl + (size_t)s * ND + c) = l;
}

// ============ split-fp16 MFMA GEMM: C = A_hl(M,K) * B_hl(N,K)^T ==============
template<int MODE>
__global__ __launch_bounds__(256) void k_gemm_hl(
    const half_t* __restrict__ Ah, const half_t* __restrict__ Al, long long sAz,
    const half_t* __restrict__ Bh, const half_t* __restrict__ Bl, long long sBz,
    int lda, int ldb, int K,
    float* __restrict__ Cf, half_t* __restrict__ Ch, half_t* __restrict__ Cl,
    long long sCz, int ldc,
    const float* __restrict__ xres, const float* __restrict__ mods)
{
  int z = blockIdx.z;
  int m0 = blockIdx.x * 128, n0 = blockIdx.y * 128;
  __shared__ __align__(16) char smem[40960];
  half_t* Ash = (half_t*)smem;
  half_t* Asl = (half_t*)(smem + 10240);
  half_t* Bsh = (half_t*)(smem + 20480);
  half_t* Bsl = (half_t*)(smem + 30720);
  int tid = threadIdx.x;
  int lane = tid & 63, w = tid >> 6;
  int wm = (w >> 1) * 64, wn = (w & 1) * 64;
  int qd = lane >> 4, md = lane & 15;
  int rA0 = tid >> 2, sA0 = (tid & 3) * 8;
  int rA1 = rA0 + 64;

  const half_t* pAh0 = Ah + z * sAz + (size_t)(m0 + rA0) * lda + sA0;
  const half_t* pAh1 = Ah + z * sAz + (size_t)(m0 + rA1) * lda + sA0;
  const half_t* pAl0 = Al + z * sAz + (size_t)(m0 + rA0) * lda + sA0;
  const half_t* pAl1 = Al + z * sAz + (size_t)(m0 + rA1) * lda + sA0;
  const half_t* pBh0 = Bh + z * sBz + (size_t)(n0 + rA0) * ldb + sA0;
  const half_t* pBh1 = Bh + z * sBz + (size_t)(n0 + rA1) * ldb + sA0;
  const half_t* pBl0 = Bl + z * sBz + (size_t)(n0 + rA0) * ldb + sA0;
  const half_t* pBl1 = Bl + z * sBz + (size_t)(n0 + rA1) * ldb + sA0;

  f32x4 acc[4][4];
  #pragma unroll
  for (int i = 0; i < 4; ++i)
    #pragma unroll
    for (int j = 0; j < 4; ++j)
      #pragma unroll
      for (int p = 0; p < 4; ++p) acc[i][j][p] = 0.f;

  f16x8 rah0 = *(const f16x8*)pAh0, rah1 = *(const f16x8*)pAh1;
  f16x8 ral0 = *(const f16x8*)pAl0, ral1 = *(const f16x8*)pAl1;
  f16x8 rbh0 = *(const f16x8*)pBh0, rbh1 = *(const f16x8*)pBh1;
  f16x8 rbl0 = *(const f16x8*)pBl0, rbl1 = *(const f16x8*)pBl1;

  int iters = K >> 5;
  #pragma unroll 1
  for (int it = 0; it < iters; ++it) {
    __syncthreads();
    *(f16x8*)(Ash + rA0 * LDH + sA0) = rah0;
    *(f16x8*)(Ash + rA1 * LDH + sA0) = rah1;
    *(f16x8*)(Asl + rA0 * LDH + sA0) = ral0;
    *(f16x8*)(Asl + rA1 * LDH + sA0) = ral1;
    *(f16x8*)(Bsh + rA0 * LDH + sA0) = rbh0;
    *(f16x8*)(Bsh + rA1 * LDH + sA0) = rbh1;
    *(f16x8*)(Bsl + rA0 * LDH + sA0) = rbl0;
    *(f16x8*)(Bsl + rA1 * LDH + sA0) = rbl1;
    __syncthreads();
    if (it < iters - 1) {
      int k1 = (it + 1) * 32;
      rah0 = *(const f16x8*)(pAh0 + k1); rah1 = *(const f16x8*)(pAh1 + k1);
      ral0 = *(const f16x8*)(pAl0 + k1); ral1 = *(const f16x8*)(pAl1 + k1);
      rbh0 = *(const f16x8*)(pBh0 + k1); rbh1 = *(const f16x8*)(pBh1 + k1);
      rbl0 = *(const f16x8*)(pBl0 + k1); rbl1 = *(const f16x8*)(pBl1 + k1);
    }
    f16x8 ah[4], al[4], bh[4], bl[4];
    #pragma unroll
    for (int i = 0; i < 4; ++i) {
      ah[i] = *(const f16x8*)(Ash + (wm + 16 * i + md) * LDH + qd * 8);
      al[i] = *(const f16x8*)(Asl + (wm + 16 * i + md) * LDH + qd * 8);
    }
    #pragma unroll
    for (int j = 0; j < 4; ++j) {
      bh[j] = *(const f16x8*)(Bsh + (wn + 16 * j + md) * LDH + qd * 8);
      bl[j] = *(const f16x8*)(Bsl + (wn + 16 * j + md) * LDH + qd * 8);
    }
    #pragma unroll
    for (int i = 0; i < 4; ++i)
      #pragma unroll
      for (int j = 0; j < 4; ++j) {
        acc[i][j] = __builtin_amdgcn_mfma_f32_16x16x32_f16(ah[i], bh[j], acc[i][j], 0, 0, 0);
        acc[i][j] = __builtin_amdgcn_mfma_f32_16x16x32_f16(ah[i], bl[j], acc[i][j], 0, 0, 0);
        acc[i][j] = __builtin_amdgcn_mfma_f32_16x16x32_f16(al[i], bh[j], acc[i][j], 0, 0, 0);
      }
  }

  if (MODE == 1) {
    half_t* Cs = (half_t*)smem;
    __syncthreads();
    #pragma unroll
    for (int i = 0; i < 4; ++i)
      #pragma unroll
      for (int j = 0; j < 4; ++j)
        #pragma unroll
        for (int p = 0; p < 4; ++p)
          Cs[(wm + 16 * i + qd * 4 + p) * LDC + wn + 16 * j + md] = (half_t)acc[i][j][p];
    __syncthreads();
    #pragma unroll
    for (int it2 = 0; it2 < 8; ++it2) {
      int chunk = it2 * 256 + tid;
      int r = chunk >> 4, c8 = (chunk & 15) * 8;
      *(f16x8*)(Ch + z * sCz + (size_t)(m0 + r) * ldc + n0 + c8) = *(const f16x8*)(Cs + r * LDC + c8);
    }
    __syncthreads();
    #pragma unroll
    for (int i = 0; i < 4; ++i)
      #pragma unroll
      for (int j = 0; j < 4; ++j)
        #pragma unroll
        for (int p = 0; p < 4; ++p) {
          float v = acc[i][j][p];
          half_t h = (half_t)v;
          Cs[(wm + 16 * i + qd * 4 + p) * LDC + wn + 16 * j + md] = (half_t)(v - (float)h);
        }
    __syncthreads();
    #pragma unroll
    for (int it2 = 0; it2 < 8; ++it2) {
      int chunk = it2 * 256 + tid;
      int r = chunk >> 4, c8 = (chunk & 15) * 8;
      *(f16x8*)(Cl + z * sCz + (size_t)(m0 + r) * ldc + n0 + c8) = *(const f16x8*)(Cs + r * LDC + c8);
    }
  } else {
    #pragma unroll
    for (int i = 0; i < 4; ++i)
      #pragma unroll
      for (int p = 0; p < 4; ++p) {
        int r = m0 + wm + 16 * i + qd * 4 + p;
        float* cp = Cf + z * sCz + (size_t)r * ldc + n0 + wn + md;
        if (MODE == 2) {
          int batch = r >> 10;
          const float* mb = mods + batch * D6 + 2 * ND;
          const float* xp = xres + (size_t)r * ldc + n0 + wn + md;
          #pragma unroll
          for (int j = 0; j < 4; ++j) {
            int col = wn + md + 16 * j;
            cp[16 * j] = xp[16 * j] + mb[n0 + col] * acc[i][j][p];
          }
        } else {
          #pragma unroll
          for (int j = 0; j < 4; ++j) cp[16 * j] = acc[i][j][p];
        }
      }
  }
}

// ---- softmax over rows of 512, input = 4 split-K partials; P as h/l fp16 ----
__global__ __launch_bounds__(256) void k_softmax512_sum4(const float* __restrict__ SC4,
    half_t* __restrict__ Ph, half_t* __restrict__ Pl)
{
  __shared__ float red[16];
  int tid = threadIdx.x;
  int row = blockIdx.x;             // 2048 = b*512 + d
  int b = row >> 9, d = row & 511;
  const float* r0 = SC4 + ((size_t)(b * 4 + 0) << 18) + (size_t)d * ND;
  const float* r1 = SC4 + ((size_t)(b * 4 + 1) << 18) + (size_t)d * ND;
  const float* r2 = SC4 + ((size_t)(b * 4 + 2) << 18) + (size_t)d * ND;
  const float* r3 = SC4 + ((size_t)(b * 4 + 3) << 18) + (size_t)d * ND;
  float x0 = r0[tid] + r1[tid] + r2[tid] + r3[tid];
  float x1 = r0[tid + 256] + r1[tid + 256] + r2[tid + 256] + r3[tid + 256];
  float m = fmaxf(x0, x1);
  #pragma unroll
  for (int off = 32; off > 0; off >>= 1) m = fmaxf(m, __shfl_down(m, off, 64));
  if ((tid & 63) == 0) red[tid >> 6] = m;
  __syncthreads();
  if (tid == 0) red[0] = fmaxf(fmaxf(red[0], red[1]), fmaxf(red[2], red[3]));
  __syncthreads();
  m = red[0];
  float e0 = expf(x0 - m), e1 = expf(x1 - m);
  float s = e0 + e1;
  #pragma unroll
  for (int off = 32; off > 0; off >>= 1) s += __shfl_down(s, off, 64);
  if ((tid & 63) == 0) red[8 + (tid >> 6)] = s;
  __syncthreads();
  if (tid == 0) red[8] = red[8] + red[9] + red[10] + red[11];
  __syncthreads();
  float inv = 1.f / red[8];
  float p0 = e0 * inv, p1 = e1 * inv;
  size_t base = (size_t)row * ND;
  half_t h0 = (half_t)p0, h1 = (half_t)p1;
  Ph[base + tid] = h0;       Pl[base + tid] = (half_t)(p0 - (float)h0);
  Ph[base + tid + 256] = h1; Pl[base + tid + 256] = (half_t)(p1 - (float)h1);
}

// -------- router logits = xm @ Wr + br  (T x 8) ------------------------------
__global__ __launch_bounds__(256) void k_router(const float* __restrict__ xm,
    const float* __restrict__ Wr, const float* __restrict__ br, float* __restrict__ logits)
{
  int idx = blockIdx.x * 256 + threadIdx.x;
  int t = idx >> 3, e = idx & 7;
  float acc = br[e];
  const float* xr = xm + (size_t)t * ND;
  #pragma unroll 4
  for (int d = 0; d < ND; ++d) acc += xr[d] * Wr[d * NE + e];
  logits[idx] = acc;
}

// -------- nrm[b,e] = sqrt(sum_s logits^2); also zeroes cnt[0..15] ------------
__global__ __launch_bounds__(256) void k_colnorm(const float* __restrict__ logits,
    float* __restrict__ nrm, int* __restrict__ cnt)
{
  __shared__ float red[8];
  int tid = threadIdx.x;
  if (blockIdx.x == 0 && tid < 16) cnt[tid] = 0;
  int b = blockIdx.x >> 3, e = blockIdx.x & 7;
  float acc = 0.f;
  for (int s = tid; s < NS; s += 256) {
    float l = logits[((size_t)(b << 10) + s) * NE + e];
    acc += l * l;
  }
  #pragma unroll
  for (int off = 32; off > 0; off >>= 1) acc += __shfl_down(acc, off, 64);
  if ((tid & 63) == 0) red[tid >> 6] = acc;
  __syncthreads();
  if (tid == 0) nrm[b * NE + e] = sqrtf(red[0] + red[1] + red[2] + red[3]);
}

// -------- per-token: probs, top-2, expert counts -----------------------------
__global__ __launch_bounds__(256) void k_top2(const float* __restrict__ logits,
    const float* __restrict__ nrm, float* __restrict__ probs,
    float* __restrict__ wsel, int* __restrict__ isel, int* __restrict__ cnt)
{
  int t = blockIdx.x * 256 + threadIdx.x;
  int b = t >> 10;
  float p[NE];
  float mx = -1e30f;
  #pragma unroll
  for (int e = 0; e < NE; ++e) {
    float l = logits[t * NE + e] / fmaxf(nrm[b * NE + e], 1e-12f);
    p[e] = l;
    mx = fmaxf(mx, l);
  }
  float s = 0.f;
  #pragma unroll
  for (int e = 0; e < NE; ++e) { p[e] = expf(p[e] - mx); s += p[e]; }
  float inv = 1.f / s;
  #pragma unroll
  for (int e = 0; e < NE; ++e) { p[e] *= inv; probs[t * NE + e] = p[e]; }
  int i1 = 0;
  #pragma unroll
  for (int e = 1; e < NE; ++e) if (p[e] > p[i1]) i1 = e;
  int i2 = (i1 == 0) ? 1 : 0;
  #pragma unroll
  for (int e = 0; e < NE; ++e) if (e != i1 && p[e] > p[i2]) i2 = e;
  wsel[t * 2] = p[i1]; wsel[t * 2 + 1] = p[i2];
  isel[t * 2] = i1;    isel[t * 2 + 1] = i2;
  atomicAdd(&cnt[i1], 1); atomicAdd(&cnt[i2], 1);
}

__global__ void k_scan(const int* __restrict__ cnt, int* __restrict__ offs)
{
  if (threadIdx.x == 0) {
    int a = 0;
    for (int e = 0; e < NE; ++e) { offs[e] = a; a += cnt[e]; }
    offs[NE] = a;
  }
}

// fill: compacted per-expert token lists + token->slot inverse map
__global__ __launch_bounds__(256) void k_fill(const int* __restrict__ isel,
    const int* __restrict__ offs, int* __restrict__ cnt2,
    int* __restrict__ list, int* __restrict__ inv)
{
  int idx = blockIdx.x * 256 + threadIdx.x;   // 8192 = token*2 + k
  int e = isel[idx];
  int pos = atomicAdd(&cnt2[e], 1);
  int slot = offs[e] + pos;
  list[slot] = idx >> 1;
  inv[idx] = slot;
}

// -------- aux = sum_{s,e} (1/E - mean_b probs)^2 -----------------------------
__global__ __launch_bounds__(256) void k_aux(const float* __restrict__ probs,
    float* __restrict__ outAux)
{
  __shared__ float red[8];
  int tid = threadIdx.x;
  float acc = 0.f;
  for (int s = tid; s < NS; s += 256) {
    #pragma unroll
    for (int e = 0; e < NE; ++e) {
      float a = probs[(size_t)s * NE + e] + probs[(size_t)(NS + s) * NE + e]
              + probs[(size_t)(2 * NS + s) * NE + e] + probs[(size_t)(3 * NS + s) * NE + e];
      float d = 0.125f - a * 0.25f;
      acc += d * d;
    }
  }
  #pragma unroll
  for (int off = 32; off > 0; off >>= 1) acc += __shfl_down(acc, off, 64);
  if ((tid & 63) == 0) red[tid >> 6] = acc;
  __syncthreads();
  if (tid == 0) *outAux = red[0] + red[1] + red[2] + red[3];
}

// ---- transpose+cast W1 and W3 in one launch: z = sel*8 + e ------------------
__global__ __launch_bounds__(256) void k_tcast13(const float* __restrict__ W1,
    const float* __restrict__ W3, half_t* __restrict__ W1t, half_t* __restrict__ W3t)
{
  __shared__ float tile[32][33];
  int z = blockIdx.z;
  int sel = z >> 3, e = z & 7;
  const float* We = (sel ? W3 : W1) + (size_t)e * ND * NH;
  half_t* Wte = (sel ? W3t : W1t) + (size_t)e * ND * NH;
  int k0 = blockIdx.x * 32, n0 = blockIdx.y * 32;
  int tid = threadIdx.x;
  int r = tid >> 5, c = tid & 31;
  #pragma unroll
  for (int p = 0; p < 4; ++p)
    tile[r + p * 8][c] = We[(size_t)(k0 + r + p * 8) * NH + n0 + c];
  __syncthreads();
  #pragma unroll
  for (int p = 0; p < 4; ++p)
    Wte[(size_t)(n0 + r + p * 8) * ND + k0 + c] = (half_t)tile[c][r + p * 8];
}

// ---- transpose+cast W2[e][NH][ND] -> W2t[e][ND][NH] -------------------------
__global__ __launch_bounds__(256) void k_tcastW2(const float* __restrict__ W,
    half_t* __restrict__ Wt)
{
  __shared__ float tile[32][33];
  const float* We = W + (size_t)blockIdx.z * NH * ND;
  half_t* Wte = Wt + (size_t)blockIdx.z * NH * ND;
  int k0 = blockIdx.x * 32, n0 = blockIdx.y * 32;
  int tid = threadIdx.x;
  int r = tid >> 5, c = tid & 31;
  #pragma unroll
  for (int p = 0; p < 4; ++p)
    tile[r + p * 8][c] = We[(size_t)(k0 + r + p * 8) * ND + n0 + c];
  __syncthreads();
  #pragma unroll
  for (int p = 0; p < 4; ++p)
    Wte[(size_t)(n0 + r + p * 8) * NH + k0 + c] = (half_t)tile[c][r + p * 8];
}

// ============ fused FFN: gate = f16( sin(xm@W1^T) * (xm@W3^T) ) ==============
// flat grid, expert = bx & 7 (XCD-affine). depth-2 register prefetch.
__global__ __launch_bounds__(256) void k_ffn_fused(const half_t* __restrict__ xmh,
    const half_t* __restrict__ W1t, const half_t* __restrict__ W3t,
    const int* __restrict__ list, const int* __restrict__ offs,
    half_t* __restrict__ gate)
{
  int bx = blockIdx.x;            // 1536 = 8 e * 16 m * 12 n
  int e = bx & 7;
  int r6 = bx >> 3;
  int m0 = (r6 & 15) * 128;
  int n0 = (r6 >> 4) * 128;
  int base = offs[e], ne = offs[e + 1] - base;
  if (m0 >= ne) return;
  __shared__ __align__(16) char smem[35328];
  half_t* As  = (half_t*)smem;               // 10240
  half_t* B1s = (half_t*)(smem + 10240);     // 10240
  half_t* B3s = (half_t*)(smem + 20480);     // 10240
  half_t* Cs  = (half_t*)smem;               // 34816 (epilogue reuse)
  int* rowt   = (int*)(smem + 34816);        // 512 (survives epilogue)
  int tid = threadIdx.x;
  if (tid < 128) {
    int rr = m0 + tid;
    rowt[tid] = (rr < ne) ? list[base + rr] : -1;
  }
  __syncthreads();
  const half_t* B1g = W1t + ((size_t)e * NH + n0) * ND;
  const half_t* B3g = W3t + ((size_t)e * NH + n0) * ND;
  int lane = tid & 63, w = tid >> 6;
  int wm = (w >> 1) * 64, wn = (w & 1) * 64;
  int qd = lane >> 4, md = lane & 15;
  int rA0 = tid >> 2, sA0 = (tid & 3) * 8;
  int rA1 = rA0 + 64;
  int tok0 = rowt[rA0], tok1 = rowt[rA1];

  f16x8 zv;
  #pragma unroll
  for (int i = 0; i < 8; ++i) zv[i] = (half_t)0.f;

  const half_t* pA0 = xmh + (size_t)(tok0 < 0 ? 0 : tok0) * ND + sA0;
  const half_t* pA1 = xmh + (size_t)(tok1 < 0 ? 0 : tok1) * ND + sA0;
  const half_t* pB10 = B1g + (size_t)rA0 * ND + sA0;
  const half_t* pB11 = B1g + (size_t)rA1 * ND + sA0;
  const half_t* pB30 = B3g + (size_t)rA0 * ND + sA0;
  const half_t* pB31 = B3g + (size_t)rA1 * ND + sA0;

  f32x4 acc1[4][4], acc3[4][4];
  #pragma unroll
  for (int i = 0; i < 4; ++i)
    #pragma unroll
    for (int j = 0; j < 4; ++j)
      #pragma unroll
      for (int p = 0; p < 4; ++p) { acc1[i][j][p] = 0.f; acc3[i][j][p] = 0.f; }

  // depth-2 prefetch: two register sets in flight
  f16x8 a0_0 = (tok0 >= 0) ? *(const f16x8*)(pA0) : zv;
  f16x8 a1_0 = (tok1 >= 0) ? *(const f16x8*)(pA1) : zv;
  f16x8 b10_0 = *(const f16x8*)(pB10), b11_0 = *(const f16x8*)(pB11);
  f16x8 b30_0 = *(const f16x8*)(pB30), b31_0 = *(const f16x8*)(pB31);
  f16x8 a0_1 = (tok0 >= 0) ? *(const f16x8*)(pA0 + 32) : zv;
  f16x8 a1_1 = (tok1 >= 0) ? *(const f16x8*)(pA1 + 32) : zv;
  f16x8 b10_1 = *(const f16x8*)(pB10 + 32), b11_1 = *(const f16x8*)(pB11 + 32);
  f16x8 b30_1 = *(const f16x8*)(pB30 + 32), b31_1 = *(const f16x8*)(pB31 + 32);

  #pragma unroll 1
  for (int it = 0; it < 16; it += 2) {
    // phase 0: consume set0, prefetch it+2
    __syncthreads();
    *(f16x8*)(As  + rA0 * LDH + sA0) = a0_0;
    *(f16x8*)(As  + rA1 * LDH + sA0) = a1_0;
    *(f16x8*)(B1s + rA0 * LDH + sA0) = b10_0;
    *(f16x8*)(B1s + rA1 * LDH + sA0) = b11_0;
    *(f16x8*)(B3s + rA0 * LDH + sA0) = b30_0;
    *(f16x8*)(B3s + rA1 * LDH + sA0) = b31_0;
    __syncthreads();
    if (it + 2 < 16) {
      int k2 = (it + 2) * 32;
      a0_0 = (tok0 >= 0) ? *(const f16x8*)(pA0 + k2) : zv;
      a1_0 = (tok1 >= 0) ? *(const f16x8*)(pA1 + k2) : zv;
      b10_0 = *(const f16x8*)(pB10 + k2); b11_0 = *(const f16x8*)(pB11 + k2);
      b30_0 = *(const f16x8*)(pB30 + k2); b31_0 = *(const f16x8*)(pB31 + k2);
    }
    {
      f16x8 a[4], b1[4], b3[4];
      #pragma unroll
      for (int i = 0; i < 4; ++i)
        a[i] = *(const f16x8*)(As + (wm + 16 * i + md) * LDH + qd * 8);
      #pragma unroll
      for (int j = 0; j < 4; ++j) {
        b1[j] = *(const f16x8*)(B1s + (wn + 16 * j + md) * LDH + qd * 8);
        b3[j] = *(const f16x8*)(B3s + (wn + 16 * j + md) * LDH + qd * 8);
      }
      #pragma unroll
      for (int i = 0; i < 4; ++i)
        #pragma unroll
        for (int j = 0; j < 4; ++j) {
          acc1[i][j] = __builtin_amdgcn_mfma_f32_16x16x32_f16(a[i], b1[j], acc1[i][j], 0, 0, 0);
          acc3[i][j] = __builtin_amdgcn_mfma_f32_16x16x32_f16(a[i], b3[j], acc3[i][j], 0, 0, 0);
        }
    }
    // phase 1: consume set1, prefetch it+3
    __syncthreads();
    *(f16x8*)(As  + rA0 * LDH + sA0) = a0_1;
    *(f16x8*)(As  + rA1 * LDH + sA0) = a1_1;
    *(f16x8*)(B1s + rA0 * LDH + sA0) = b10_1;
    *(f16x8*)(B1s + rA1 * LDH + sA0) = b11_1;
    *(f16x8*)(B3s + rA0 * LDH + sA0) = b30_1;
    *(f16x8*)(B3s + rA1 * LDH + sA0) = b31_1;
    __syncthreads();
    if (it + 3 < 16) {
      int k3 = (it + 3) * 32;
      a0_1 = (tok0 >= 0) ? *(const f16x8*)(pA0 + k3) : zv;
      a1_1 = (tok1 >= 0) ? *(const f16x8*)(pA1 + k3) : zv;
      b10_1 = *(const f16x8*)(pB10 + k3); b11_1 = *(const f16x8*)(pB11 + k3);
      b30_1 = *(const f16x8*)(pB30 + k3); b31_1 = *(const f16x8*)(pB31 + k3);
    }
    {
      f16x8 a[4], b1[4], b3[4];
      #pragma unroll
      for (int i = 0; i < 4; ++i)
        a[i] = *(const f16x8*)(As + (wm + 16 * i + md) * LDH + qd * 8);
      #pragma unroll
      for (int j = 0; j < 4; ++j) {
        b1[j] = *(const f16x8*)(B1s + (wn + 16 * j + md) * LDH + qd * 8);
        b3[j] = *(const f16x8*)(B3s + (wn + 16 * j + md) * LDH + qd * 8);
      }
      #pragma unroll
      for (int i = 0; i < 4; ++i)
        #pragma unroll
        for (int j = 0; j < 4; ++j) {
          acc1[i][j] = __builtin_amdgcn_mfma_f32_16x16x32_f16(a[i], b1[j], acc1[i][j], 0, 0, 0);
          acc3[i][j] = __builtin_amdgcn_mfma_f32_16x16x32_f16(a[i], b3[j], acc3[i][j], 0, 0, 0);
        }
    }
  }
  __syncthreads();
  #pragma unroll
  for (int i = 0; i < 4; ++i)
    #pragma unroll
    for (int j = 0; j < 4; ++j)
      #pragma unroll
      for (int p = 0; p < 4; ++p) {
        int rr = wm + 16 * i + qd * 4 + p;
        int cc = wn + 16 * j + md;
        Cs[rr * LDC + cc] = (half_t)(__sinf(acc1[i][j][p]) * acc3[i][j][p]);
      }
  __syncthreads();
  #pragma unroll
  for (int it = 0; it < 8; ++it) {
    int chunk = it * 256 + tid;
    int rr = chunk >> 4, c8 = (chunk & 15) * 8;
    if (m0 + rr < ne) {
      *(f16x8*)(gate + (size_t)(base + m0 + rr) * NH + n0 + c8) = *(const f16x8*)(Cs + rr * LDC + c8);
    }
  }
}

// ======= MoE stage 2 (atomic-free): P[slot][d] = gate[slot,:] @ W2_e^T =======
// flat grid, expert = bx & 7 (XCD-affine). depth-2 register prefetch, K=1536.
__global__ __launch_bounds__(256) void k_moe2_mfma(const half_t* __restrict__ gate,
    const half_t* __restrict__ W2t, const int* __restrict__ offs,
    float* __restrict__ P)
{
  int bx = blockIdx.x;            // 512 = 8 e * 16 m * 4 n
  int e = bx & 7;
  int r6 = bx >> 3;
  int m0 = (r6 & 15) * 128;
  int n0 = (r6 >> 4) * 128;
  int base = offs[e], ne = offs[e + 1] - base;
  if (m0 >= ne) return;
  __shared__ half_t As[128 * LDH];
  __shared__ half_t Bs[128 * LDH];
  int tid = threadIdx.x;
  const half_t* B2g = W2t + ((size_t)e * ND + n0) * NH;
  int lane = tid & 63, w = tid >> 6;
  int wm = (w >> 1) * 64, wn = (w & 1) * 64;
  int qd = lane >> 4, md = lane & 15;
  int rA0 = tid >> 2, sA0 = (tid & 3) * 8;
  int rA1 = rA0 + 64;
  bool v0 = (m0 + rA0) < ne, v1 = (m0 + rA1) < ne;

  const half_t* pA0 = gate + (size_t)(base + (v0 ? m0 + rA0 : 0)) * NH + sA0;
  const half_t* pA1 = gate + (size_t)(base + (v1 ? m0 + rA1 : 0)) * NH + sA0;
  const half_t* pB0 = B2g + (size_t)rA0 * NH + sA0;
  const half_t* pB1 = B2g + (size_t)rA1 * NH + sA0;

  f32x4 acc[4][4];
  #pragma unroll
  for (int i = 0; i < 4; ++i)
    #pragma unroll
    for (int j = 0; j < 4; ++j)
      #pragma unroll
      for (int p = 0; p < 4; ++p) acc[i][j][p] = 0.f;

  f16x8 a0_0 = *(const f16x8*)(pA0),      a1_0 = *(const f16x8*)(pA1);
  f16x8 b0_0 = *(const f16x8*)(pB0),      b1_0 = *(const f16x8*)(pB1);
  f16x8 a0_1 = *(const f16x8*)(pA0 + 32), a1_1 = *(const f16x8*)(pA1 + 32);
  f16x8 b0_1 = *(const f16x8*)(pB0 + 32), b1_1 = *(const f16x8*)(pB1 + 32);

  #pragma unroll 1
  for (int it = 0; it < 48; it += 2) {
    __syncthreads();
    *(f16x8*)(As + rA0 * LDH + sA0) = a0_0;
    *(f16x8*)(As + rA1 * LDH + sA0) = a1_0;
    *(f16x8*)(Bs + rA0 * LDH + sA0) = b0_0;
    *(f16x8*)(Bs + rA1 * LDH + sA0) = b1_0;
    __syncthreads();
    if (it + 2 < 48) {
      int k2 = (it + 2) * 32;
      a0_0 = *(const f16x8*)(pA0 + k2); a1_0 = *(const f16x8*)(pA1 + k2);
      b0_0 = *(const f16x8*)(pB0 + k2); b1_0 = *(const f16x8*)(pB1 + k2);
    }
    {
      f16x8 a[4], b[4];
      #pragma unroll
      for (int i = 0; i < 4; ++i)
        a[i] = *(const f16x8*)(As + (wm + 16 * i + md) * LDH + qd * 8);
      #pragma unroll
      for (int j = 0; j < 4; ++j)
        b[j] = *(const f16x8*)(Bs + (wn + 16 * j + md) * LDH + qd * 8);
      #pragma unroll
      for (int i = 0; i < 4; ++i)
        #pragma unroll
        for (int j = 0; j < 4; ++j)
          acc[i][j] = __builtin_amdgcn_mfma_f32_16x16x32_f16(a[i], b[j], acc[i][j], 0, 0, 0);
    }
    __syncthreads();
    *(f16x8*)(As + rA0 * LDH + sA0) = a0_1;
    *(f16x8*)(As + rA1 * LDH + sA0) = a1_1;
    *(f16x8*)(Bs + rA0 * LDH + sA0) = b0_1;
    *(f16x8*)(Bs + rA1 * LDH + sA0) = b1_1;
    __syncthreads();
    if (it + 3 < 48) {
      int k3 = (it + 3) * 32;
      a0_1 = *(const f16x8*)(pA0 + k3); a1_1 = *(const f16x8*)(pA1 + k3);
      b0_1 = *(const f16x8*)(pB0 + k3); b1_1 = *(const f16x8*)(pB1 + k3);
    }
    {
      f16x8 a[4], b[4];
      #pragma unroll
      for (int i = 0; i < 4; ++i)
        a[i] = *(const f16x8*)(As + (wm + 16 * i + md) * LDH + qd * 8);
      #pragma unroll
      for (int j = 0; j < 4; ++j)
        b[j] = *(const f16x8*)(Bs + (wn + 16 * j + md) * LDH + qd * 8);
      #pragma unroll
      for (int i = 0; i < 4; ++i)
        #pragma unroll
        for (int j = 0; j < 4; ++j)
          acc[i][j] = __builtin_amdgcn_mfma_f32_16x16x32_f16(a[i], b[j], acc[i][j], 0, 0, 0);
    }
  }
  #pragma unroll
  for (int i = 0; i < 4; ++i)
    #pragma unroll
    for (int p = 0; p < 4; ++p) {
      int gr = m0 + wm + 16 * i + qd * 4 + p;
      if (gr < ne) {
        float* pp = P + (size_t)(base + gr) * ND + n0 + wn + md;
        #pragma unroll
        for (int j = 0; j < 4; ++j)
          pp[16 * j] = acc[i][j][p];
      }
    }
}

// ---- reduce: out[t][:] = w1 * P[slot1][:] + w2 * P[slot2][:] ----------------
__global__ __launch_bounds__(256) void k_moe_reduce(const float* __restrict__ P,
    const int* __restrict__ inv, const float* __restrict__ wsel,
    float* __restrict__ out)
{
  int i = blockIdx.x * 256 + threadIdx.x;   // 4096 * 128 float4s
  int t = i >> 7, d4 = i & 127;
  int s1 = inv[t * 2], s2 = inv[t * 2 + 1];
  float w1 = wsel[t * 2], w2 = wsel[t * 2 + 1];
  const float4* P4 = (const float4*)P;
  float4 a = P4[(size_t)s1 * 128 + d4];
  float4 b = P4[(size_t)s2 * 128 + d4];
  float4 o;
  o.x = w1 * a.x + w2 * b.x;
  o.y = w1 * a.y + w2 * b.y;
  o.z = w1 * a.z + w2 * b.z;
  o.w = w1 * a.w + w2 * b.w;
  ((float4*)out)[i] = o;
}

// ---------------- workspace layout (byte offsets, peak ~63.4 MB) -------------
static const size_t BO_MODS  = 0;          // 49152 B fp32 mods
static const size_t BO_HH    = 65536;      // Hh 4 MB   } region B (8 MB)
static const size_t BO_HL2   = 4259840;    // Hl 4 MB   }
static const size_t BO_PH    = 4259840;    // Ph 2 MB (after Hl dead)
static const size_t BO_PL    = 6357056;    // Pl 2 MB
static const size_t BO_WALLH = 8454144;    // 2 MB: q|k|v|o transposed h (2048 rows)
static const size_t BO_WALLL = 10551296;   // 2 MB: l planes
static const size_t BO_QKV   = 12648448;   // fp32 [4096][1536] 25.17 MB (region D)
static const size_t BO_A0H   = 12648448;   // attn0 h 4 MB (after QKV dead)
static const size_t BO_A0L   = 16842752;   // attn0 l 4 MB
static const size_t BO_SC4   = 21037056;   // 16 MB fp32: 16 x [512][512] split-K partials
static const size_t BO_X2    = 21037056;   // fp32 8 MB (after SC4 dead)
static const size_t BO_XM    = 29425664;   // fp32 8 MB (after SC4 dead)
static const size_t BO_QTH   = 37814272;   // qT h 4 MB } region E (16 MB)
static const size_t BO_QTL   = 42008576;
static const size_t BO_KTH   = 46202880;
static const size_t BO_KTL   = 50397184;
static const size_t BO_VH    = 54591488;   // region F (8 MB)
static const size_t BO_VL    = 58785792;
// MoE phase (aliases):
static const size_t BO_W1T   = 37814272;   // 12.58 MB (qT/kT dead after scores)
static const size_t BO_XMH   = 50397184;   // 4 MB (kT_l dead)
static const size_t BO_W3T   = 65536;      // 12.58 MB = region B+C (dead after apply/Wo)
static const size_t BO_GATE  = 12648448;   // 25.17 MB = region D
static const size_t BO_W2T   = 65536;      // 12.58 MB (overwrites W3T after ffn)
static const size_t BO_P     = 37814272;   // 16.78 MB fp32 (W1T+XMH dead after ffn)
// small buffers:
static const size_t BO_LOGI  = 62980096;
static const size_t BO_NRM   = 63111168;
static const size_t BO_PROB  = 63111296;
static const size_t BO_WSEL  = 63242368;
static const size_t BO_INTS  = 63307904;   // ints: isel 8192|cnt 8|cnt2 8|offs 16|list 8192|inv 8192

extern "C" void kernel_launch(void* const* d_in, const int* in_sizes, int n_in,
                              void* d_out, int out_size, void* d_ws, size_t ws_size,
                              hipStream_t stream)
{
  const float* x    = (const float*)d_in[0];
  const float* c    = (const float*)d_in[1];
  const float* Wada = (const float*)d_in[2];
  const float* bada = (const float*)d_in[3];
  const float* Wq   = (const float*)d_in[4];
  const float* Wk   = (const float*)d_in[5];
  const float* Wv   = (const float*)d_in[6];
  const float* Wo   = (const float*)d_in[7];
  const float* qn_w = (const float*)d_in[8];
  const float* qn_b = (const float*)d_in[9];
  const float* kn_w = (const float*)d_in[10];
  const float* kn_b = (const float*)d_in[11];
  const float* an_w = (const float*)d_in[12];
  const float* an_b = (const float*)d_in[13];
  const float* fn_w = (const float*)d_in[14];
  const float* fn_b = (const float*)d_in[15];
  const float* Wr   = (const float*)d_in[16];
  const float* br   = (const float*)d_in[17];
  const float* W1   = (const float*)d_in[18];
  const float* W2   = (const float*)d_in[19];
  const float* W3   = (const float*)d_in[20];
  float* out = (float*)d_out;
  char*  ws8 = (char*)d_ws;
  float* MODS = (float*)(ws8 + BO_MODS);
  half_t* Hh = (half_t*)(ws8 + BO_HH),   *Hl = (half_t*)(ws8 + BO_HL2);
  half_t* Ph = (half_t*)(ws8 + BO_PH),   *Pl = (half_t*)(ws8 + BO_PL);
  half_t* WALLH = (half_t*)(ws8 + BO_WALLH), *WALLL = (half_t*)(ws8 + BO_WALLL);
  half_t* WoTh = WALLH + (size_t)1536 * ND,  *WoTl = WALLL + (size_t)1536 * ND;
  float* QKV = (float*)(ws8 + BO_QKV);
  half_t* A0h = (half_t*)(ws8 + BO_A0H), *A0l = (half_t*)(ws8 + BO_A0L);
  float* SC4 = (float*)(ws8 + BO_SC4);
  float* X2  = (float*)(ws8 + BO_X2);
  float* XM  = (float*)(ws8 + BO_XM);
  half_t* qTh = (half_t*)(ws8 + BO_QTH), *qTl = (half_t*)(ws8 + BO_QTL);
  half_t* kTh = (half_t*)(ws8 + BO_KTH), *kTl = (half_t*)(ws8 + BO_KTL);
  half_t* Vh  = (half_t*)(ws8 + BO_VH),  *Vl  = (half_t*)(ws8 + BO_VL);
  half_t* W1T = (half_t*)(ws8 + BO_W1T);
  half_t* W3T = (half_t*)(ws8 + BO_W3T);
  half_t* W2T = (half_t*)(ws8 + BO_W2T);
  half_t* XMH = (half_t*)(ws8 + BO_XMH);
  half_t* GATEH = (half_t*)(ws8 + BO_GATE);
  float* PBUF = (float*)(ws8 + BO_P);
  float* LOGI = (float*)(ws8 + BO_LOGI);
  float* NRM  = (float*)(ws8 + BO_NRM);
  float* PROB = (float*)(ws8 + BO_PROB);
  float* WSEL = (float*)(ws8 + BO_WSEL);
  int* ib   = (int*)(ws8 + BO_INTS);
  int* isel = ib;
  int* cnt  = ib + 8192;
  int* cnt2 = ib + 8200;
  int* offs = ib + 8208;
  int* list = ib + 8224;
  int* inv  = ib + 16416;

  k_ada<<<48, 256, 0, stream>>>(c, Wada, bada, MODS);
  k_wsplit4<<<dim3(16, 16, 4), 256, 0, stream>>>(Wq, Wk, Wv, Wo, WALLH, WALLL);
  // h = modulate(LN(x)) -> h/l planes
  k_lnmod<<<NT, 256, 0, stream>>>(x, ND, nullptr, Hh, Hl, ND, an_w, an_b, MODS, 0, 512);
  // fused QKV: [4096][1536]
  k_gemm_hl<0><<<dim3(32, 12, 1), 256, 0, stream>>>(Hh, Hl, 0, WALLH, WALLL, 0,
      ND, ND, ND, QKV, nullptr, nullptr, 0, 1536, nullptr, nullptr);
  // fused row-LN of q and k halves (in place)
  k_lnqk<<<2 * NT, 256, 0, stream>>>(QKV, qn_w, qn_b, kn_w, kn_b);
  // transpose+split q,k to [d][s]; split v
  k_tsplit2<<<dim3(128, 16, 2), 256, 0, stream>>>(QKV, qTh, qTl);
  k_vsplit<<<2048, 256, 0, stream>>>(QKV, Vh, Vl);
  // scores: split-K x4 (z = b*4+kh; A/B offset z*256 = b*1024+kh*256)
  k_gemm_hl<0><<<dim3(4, 4, 16), 256, 0, stream>>>(qTh, qTl, 256, kTh, kTl, 256,
      NT, NT, 256, SC4, nullptr, nullptr, 262144, ND, nullptr, nullptr);
  k_softmax512_sum4<<<2048, 256, 0, stream>>>(SC4, Ph, Pl);
  // apply: attn0[s][d] = sum_e v[s,e] P[d,e]
  k_gemm_hl<1><<<dim3(8, 4, 4), 256, 0, stream>>>(Vh, Vl, 524288, Ph, Pl, 262144,
      ND, ND, ND, nullptr, A0h, A0l, 524288, ND, nullptr, nullptr);
  // Wo + residual: X2 = x + g_msa * (attn0 @ Wo)
  k_gemm_hl<2><<<dim3(32, 4, 1), 256, 0, stream>>>(A0h, A0l, 0, WoTh, WoTl, 0,
      ND, ND, ND, X2, nullptr, nullptr, 0, ND, x, MODS);
  // xm = modulate(LN(X2)) -> fp32 (router) + fp16 (ffn)
  k_lnmod<<<NT, 256, 0, stream>>>(X2, ND, XM, XMH, nullptr, ND, fn_w, fn_b, MODS, 1536, 2048);
  // routing
  k_router<<<128, 256, 0, stream>>>(XM, Wr, br, LOGI);
  k_colnorm<<<32, 256, 0, stream>>>(LOGI, NRM, cnt);
  k_top2<<<16, 256, 0, stream>>>(LOGI, NRM, PROB, WSEL, isel, cnt);
  k_scan<<<1, 64, 0, stream>>>(cnt, offs);
  k_fill<<<32, 256, 0, stream>>>(isel, offs, cnt2, list, inv);
  k_aux<<<1, 256, 0, stream>>>(PROB, out + (size_t)NT * ND);
  // MoE: fused gate (XCD-affine, depth-2), atomic-free down-proj, combine
  k_tcast13<<<dim3(16, 48, 16), 256, 0, stream>>>(W1, W3, W1T, W3T);
  k_ffn_fused<<<1536, 256, 0, stream>>>(XMH, W1T, W3T, list, offs, GATEH);
  k_tcastW2<<<dim3(48, 16, 8), 256, 0, stream>>>(W2, W2T);  // W3T dead now
  k_moe2_mfma<<<512, 256, 0, stream>>>(GATEH, W2T, offs, PBUF);
  k_moe_reduce<<<2048, 256, 0, stream>>>(PBUF, inv, WSEL, out);
}